// Round 8
// baseline (42.395 us; speedup 1.0000x reference)
//
#include <hip/hip_runtime.h>
#include <cstdint>

// Problem constants
#define BB 8
#define LL 2048
#define DD 768
#define SS 512
#define MAXW 32

constexpr int M = BB * SS;   // 4096 spans
constexpr int K = 2 * DD;    // 1536
constexpr int N = DD;        // 768

typedef __attribute__((ext_vector_type(8))) short short8;   // 8 bf16 = 4 VGPRs
typedef __attribute__((ext_vector_type(4))) float f32x4;

__device__ __forceinline__ unsigned short f2bf(float f) {
    union { float f; unsigned int u; } v; v.f = f;
    unsigned int r = v.u + 0x7fffu + ((v.u >> 16) & 1u);  // RNE
    return (unsigned short)(r >> 16);
}

// generic -> addrspace casts for global_load_lds
#define AS1(p) reinterpret_cast<const __attribute__((address_space(1))) void*>( \
                   reinterpret_cast<uintptr_t>(p))
#define AS3(p) reinterpret_cast<__attribute__((address_space(3))) void*>( \
                   reinterpret_cast<uintptr_t>(p))

// ---------------------------------------------------------------------------
// Kernel 1: WAVE-per-span gather (deep MLP) + W-transpose side blocks.
//  blocks [0, 1024): 4 waves/block, one span per wave. Lane covers row
//    float4-chunks {lane, lane+64, lane+128} (3 coalesced 1KB segments);
//    row loop unrolled x2 -> 6 loads in flight/lane (vs 2 before).
//    bid&7 = batch -> XCD L2 affinity. Writes cat bf16 (max | mean).
//  blocks [1024, 1024+1152): W_down (K x N f32) -> WT (N x K bf16).
// ---------------------------------------------------------------------------
__global__ __launch_bounds__(256) void span_wt_kernel(
    const float* __restrict__ repr,            // (B,L,D) f32
    const int*   __restrict__ spans,           // (B,S,2) int
    const float* __restrict__ W,               // (K,N) f32
    unsigned short* __restrict__ cat,          // (M, 2D) bf16
    unsigned short* __restrict__ WT)           // (N,K) bf16
{
    __shared__ float tbuf[32][33];
    const int bid = blockIdx.x;
    const int tid = threadIdx.x;

    if (bid < 1024) {
        const int wave = tid >> 6, lane = tid & 63;
        const int b = bid & 7;                       // batch -> XCD pin
        const int span = (b << 9) | (((bid >> 3) << 2) | wave);

        // int64-layout sniff (values < 2048 so high words zero under int64)
        const bool is64 = ((spans[1] | spans[3] | spans[5] | spans[7]) == 0);
        int st, en;
        if (is64) { st = spans[4 * span];     en = spans[4 * span + 2]; }
        else      { st = spans[2 * span];     en = spans[2 * span + 1]; }
        const int cnt = en - st + 1;                 // 1..32, wave-uniform

        const float4* base = (const float4*)repr + (size_t)b * LL * (DD / 4);

        float4 mx[3], sm[3];
        #pragma unroll
        for (int c = 0; c < 3; ++c) {
            mx[c] = make_float4(-3.0e38f, -3.0e38f, -3.0e38f, -3.0e38f);
            sm[c] = make_float4(0.f, 0.f, 0.f, 0.f);
        }

        #define ACC(c, v)                                              \
            mx[c].x = fmaxf(mx[c].x, (v).x); mx[c].y = fmaxf(mx[c].y, (v).y); \
            mx[c].z = fmaxf(mx[c].z, (v).z); mx[c].w = fmaxf(mx[c].w, (v).w); \
            sm[c].x += (v).x; sm[c].y += (v).y; sm[c].z += (v).z; sm[c].w += (v).w;

        int w = 0;
        if (cnt & 1) {                               // odd count: peel one row
            const float4* rp = base + (size_t)en * (DD / 4) + lane;
            const float4 a0 = rp[0], a1 = rp[64], a2 = rp[128];
            ACC(0, a0); ACC(1, a1); ACC(2, a2);
            w = 1;
        }
        for (; w < cnt; w += 2) {                    // 6 loads in flight
            const float4* r0 = base + (size_t)(en - w) * (DD / 4) + lane;
            const float4* r1 = r0 - (DD / 4);
            const float4 a0 = r0[0], a1 = r0[64], a2 = r0[128];
            const float4 b0 = r1[0], b1 = r1[64], b2 = r1[128];
            ACC(0, a0); ACC(1, a1); ACC(2, a2);
            ACC(0, b0); ACC(1, b1); ACC(2, b2);
        }
        #undef ACC

        const float inv = 1.0f / (float)cnt;
        unsigned short* crow = cat + (size_t)span * K;
        #pragma unroll
        for (int c = 0; c < 3; ++c) {
            const int d4 = c * 64 + lane;            // float4 index within row
            ushort4 omax, omean;
            omax.x  = f2bf(mx[c].x);       omax.y  = f2bf(mx[c].y);
            omax.z  = f2bf(mx[c].z);       omax.w  = f2bf(mx[c].w);
            omean.x = f2bf(sm[c].x * inv); omean.y = f2bf(sm[c].y * inv);
            omean.z = f2bf(sm[c].z * inv); omean.w = f2bf(sm[c].w * inv);
            *(ushort4*)(crow + d4 * 4)      = omax;
            *(ushort4*)(crow + DD + d4 * 4) = omean;
        }
    } else {
        // ---- W transpose+cast: 24 x 48 tiles of 32x32, 256 threads
        const int tt = bid - 1024;
        const int n0 = (tt % 24) * 32, k0 = (tt / 24) * 32;
        const int tx = tid & 31, ty = tid >> 5;      // (32, 8)
        #pragma unroll
        for (int j = 0; j < 4; ++j)
            tbuf[ty + 8 * j][tx] = W[(size_t)(k0 + ty + 8 * j) * N + n0 + tx];
        __syncthreads();
        #pragma unroll
        for (int j = 0; j < 4; ++j)
            WT[(size_t)(n0 + ty + 8 * j) * K + k0 + tx] = f2bf(tbuf[tx][ty + 8 * j]);
    }
}

// ---------------------------------------------------------------------------
// Kernel 2: out = cat(bf16) @ WT(bf16)^T + bias, MFMA 16x16x32.
// BM=BN=BK=64; 256 threads = 4 waves (2x2); wave tile 32x32.
// Double-buffered prefetch-before-compute; grid 768 = 3 blocks/CU.
// XCD swizzle: 96 tiles/XCD -> A panel 1.57 MB + WT 2.4 MB ~ L2-resident.
// (UNCHANGED from round 7 — single-lever round.)
// ---------------------------------------------------------------------------
constexpr int BM = 64, BN = 64, BK = 64;

__global__ __launch_bounds__(256) void gemm_bias_kernel(
    const unsigned short* __restrict__ A,    // (M, K)  bf16
    const unsigned short* __restrict__ WT,   // (N, K)  bf16
    const float* __restrict__ bias,          // (N)     f32
    float*       __restrict__ C)             // (M, N)  f32
{
    __shared__ unsigned short Asm[2][BM * BK];  // 2 x 8 KB, swizzled chunks
    __shared__ unsigned short Bsm[2][BN * BK];  // 2 x 8 KB

    const int tid = threadIdx.x;
    const int tile = (blockIdx.x & 7) * 96 + (blockIdx.x >> 3);
    const int mt = tile / 12, nt = tile % 12;
    const int m0 = mt * BM, n0 = nt * BN;

    const int lane = tid & 63;
    const int wid  = tid >> 6;
    const int wm = wid >> 1, wn = wid & 1;   // 2x2 wave grid, wave tile 32x32
    const int lnib = lane & 15, hi = lane >> 4;

    f32x4 acc[2][2] = {};

    auto stage = [&](int k0, int buf) {
        #pragma unroll
        for (int it = 0; it < 2; ++it) {
            const int s   = it * 256 + tid;
            const int row = s >> 3, c8 = s & 7;
            const unsigned short* g =
                A + (size_t)(m0 + row) * K + k0 + ((c8 ^ (row & 7)) << 3);
            __builtin_amdgcn_global_load_lds(AS1(g), AS3(&Asm[buf][s << 3]), 16, 0, 0);
        }
        #pragma unroll
        for (int it = 0; it < 2; ++it) {
            const int s   = it * 256 + tid;
            const int row = s >> 3, c8 = s & 7;
            const unsigned short* g =
                WT + (size_t)(n0 + row) * K + k0 + ((c8 ^ (row & 7)) << 3);
            __builtin_amdgcn_global_load_lds(AS1(g), AS3(&Bsm[buf][s << 3]), 16, 0, 0);
        }
    };

    auto compute = [&](int buf) {
        #pragma unroll
        for (int kk = 0; kk < 2; ++kk) {
            short8 af[2], bf[2];
            const int cc = kk * 4 + hi;
            #pragma unroll
            for (int mf = 0; mf < 2; ++mf) {
                const int r = wm * 32 + mf * 16 + lnib;
                af[mf] = *(const short8*)&Asm[buf][(r * 8 + (cc ^ (r & 7))) << 3];
            }
            #pragma unroll
            for (int nf = 0; nf < 2; ++nf) {
                const int r = wn * 32 + nf * 16 + lnib;
                bf[nf] = *(const short8*)&Bsm[buf][(r * 8 + (cc ^ (r & 7))) << 3];
            }
            #pragma unroll
            for (int mf = 0; mf < 2; ++mf)
                #pragma unroll
                for (int nf = 0; nf < 2; ++nf)
                    acc[mf][nf] = __builtin_amdgcn_mfma_f32_16x16x32_bf16(
                        af[mf], bf[nf], acc[mf][nf], 0, 0, 0);
        }
    };

    constexpr int NT = K / BK;   // 24 K-steps

    stage(0, 0);
    __syncthreads();             // vmcnt(0) drain: buf0 ready

    int cur = 0;
    #pragma unroll 1
    for (int t = 0; t < NT - 1; ++t) {
        stage((t + 1) * BK, cur ^ 1);  // issue next tile's loads first
        compute(cur);                   // MFMA on current while loads fly
        __syncthreads();                // next buf ready; cur free to reuse
        cur ^= 1;
    }
    compute(cur);

    // Epilogue: bias + store. C/D: col = lane&15, row = hi*4 + reg.
    #pragma unroll
    for (int nf = 0; nf < 2; ++nf) {
        const int col = n0 + wn * 32 + nf * 16 + lnib;
        const float bv = bias[col];
        #pragma unroll
        for (int mf = 0; mf < 2; ++mf) {
            const int rbase = m0 + wm * 32 + mf * 16 + hi * 4;
            #pragma unroll
            for (int r = 0; r < 4; ++r)
                C[(size_t)(rbase + r) * N + col] = acc[mf][nf][r] + bv;
        }
    }
}

// ---------------------------------------------------------------------------
extern "C" void kernel_launch(void* const* d_in, const int* in_sizes, int n_in,
                              void* d_out, int out_size, void* d_ws, size_t ws_size,
                              hipStream_t stream)
{
    const float* repr  = (const float*)d_in[0];  // (B,L,D) f32
    const int*   spans = (const int*)  d_in[1];  // (B,S,2)
    const float* Wd    = (const float*)d_in[2];  // (2D,D) f32
    const float* bias  = (const float*)d_in[3];  // (D)    f32
    float* out = (float*)d_out;                  // (M, N) f32

    unsigned short* catb = (unsigned short*)d_ws;             // M*K = 12.6 MB
    unsigned short* WT   = catb + (size_t)M * K;              // N*K =  2.4 MB

    span_wt_kernel<<<1024 + 1152, 256, 0, stream>>>(repr, spans, Wd, catb, WT);
    gemm_bias_kernel<<<768, 256, 0, stream>>>(catb, WT, bias, out);
}